// Round 2
// baseline (2208.676 us; speedup 1.0000x reference)
//
#include <hip/hip_runtime.h>
#include <hip/hip_bf16.h>

#define NNODE 1024
#define NGRAPH 4
#define EDIM 768
#define NH 12
#define HD 64
#define NBH 48          // NGRAPH*NH
#define MTOK 4096       // NNODE*NGRAPH
#define QKVN 2304       // 3*EDIM
#define ROWSTR (NGRAPH*QKVN)   // element stride between node rows in qkv ws

typedef __attribute__((ext_vector_type(8))) short bf16x8;
typedef __attribute__((ext_vector_type(4))) short bf16x4;
typedef __attribute__((ext_vector_type(4))) float f32x4;

// bf16 bits -> float
static __device__ __forceinline__ float s2f(short x) {
    union { unsigned u; float f; } c;
    c.u = ((unsigned)(unsigned short)x) << 16;
    return c.f;
}
// float -> bf16 bits, round-to-nearest-even
static __device__ __forceinline__ short f2s(float f) {
    union { float f; unsigned u; } c; c.f = f;
    unsigned r = (c.u + 0x7FFFu + ((c.u >> 16) & 1u)) >> 16;
    return (short)r;
}

// C[M,N] = A[M,K] @ B[N,K]^T + bias[N].  A,B,bias fp32; compute bf16 MFMA.
// mode 0: scale cols < EDIM by 0.125 (q scaling), C is bf16 (short*)
// mode 1: zero rows whose (b,n) mask is 0 (row = n*NGRAPH + b), C is fp32
__global__ __launch_bounds__(256) void gemm_bt(
    const float* __restrict__ A,
    const float* __restrict__ B,
    const float* __restrict__ bias,
    void* __restrict__ Cv,
    int M, int N, int K, int mode, const int* __restrict__ mask)
{
    const int BK = 32, LDK = 40;  // +8 pad to break bank-conflict strides
    __shared__ __align__(16) short As[64 * LDK];
    __shared__ __align__(16) short Bs[64 * LDK];

    const int m0 = blockIdx.x * 64;
    const int n0 = blockIdx.y * 64;
    const int t = threadIdx.x;
    const int w = t >> 6, l = t & 63;
    const int wm = (w & 1) * 32, wn = (w >> 1) * 32;
    const int ldr = t >> 2;          // 0..63
    const int ldc = (t & 3) * 8;     // 0,8,16,24

    f32x4 acc[2][2];
    #pragma unroll
    for (int i = 0; i < 2; i++)
        #pragma unroll
        for (int j = 0; j < 2; j++)
            acc[i][j] = (f32x4){0.f, 0.f, 0.f, 0.f};

    const int lr = l & 15;
    const int lk = (l >> 4) * 8;

    for (int kt = 0; kt < K; kt += BK) {
        const float* ap = A + (size_t)(m0 + ldr) * K + kt + ldc;
        const float* bp = B + (size_t)(n0 + ldr) * K + kt + ldc;
        float4 a0 = *(const float4*)(ap);
        float4 a1 = *(const float4*)(ap + 4);
        float4 b0 = *(const float4*)(bp);
        float4 b1 = *(const float4*)(bp + 4);
        bf16x8 av, bv;
        av[0] = f2s(a0.x); av[1] = f2s(a0.y); av[2] = f2s(a0.z); av[3] = f2s(a0.w);
        av[4] = f2s(a1.x); av[5] = f2s(a1.y); av[6] = f2s(a1.z); av[7] = f2s(a1.w);
        bv[0] = f2s(b0.x); bv[1] = f2s(b0.y); bv[2] = f2s(b0.z); bv[3] = f2s(b0.w);
        bv[4] = f2s(b1.x); bv[5] = f2s(b1.y); bv[6] = f2s(b1.z); bv[7] = f2s(b1.w);
        *(bf16x8*)(&As[ldr * LDK + ldc]) = av;
        *(bf16x8*)(&Bs[ldr * LDK + ldc]) = bv;
        __syncthreads();

        bf16x8 af0 = *(const bf16x8*)(&As[(wm + lr) * LDK + lk]);
        bf16x8 af1 = *(const bf16x8*)(&As[(wm + 16 + lr) * LDK + lk]);
        bf16x8 bf0 = *(const bf16x8*)(&Bs[(wn + lr) * LDK + lk]);
        bf16x8 bf1 = *(const bf16x8*)(&Bs[(wn + 16 + lr) * LDK + lk]);

        acc[0][0] = __builtin_amdgcn_mfma_f32_16x16x32_bf16(af0, bf0, acc[0][0], 0, 0, 0);
        acc[0][1] = __builtin_amdgcn_mfma_f32_16x16x32_bf16(af0, bf1, acc[0][1], 0, 0, 0);
        acc[1][0] = __builtin_amdgcn_mfma_f32_16x16x32_bf16(af1, bf0, acc[1][0], 0, 0, 0);
        acc[1][1] = __builtin_amdgcn_mfma_f32_16x16x32_bf16(af1, bf1, acc[1][1], 0, 0, 0);
        __syncthreads();
    }

    // epilogue: C/D layout col = lane&15, row = (lane>>4)*4 + reg
    const int lq = l >> 4;
    short* Cb = (short*)Cv;
    float* Cf = (float*)Cv;
    #pragma unroll
    for (int i = 0; i < 2; i++) {
        #pragma unroll
        for (int j = 0; j < 2; j++) {
            const int col = n0 + wn + j * 16 + lr;
            const float bcol = bias[col];
            #pragma unroll
            for (int r = 0; r < 4; r++) {
                const int row = m0 + wm + i * 16 + lq * 4 + r;
                float v = acc[i][j][r] + bcol;
                if (mode == 0) {
                    if (col < EDIM) v *= 0.125f;   // hd^-0.5, applied after bias like ref
                    Cb[(size_t)row * N + col] = f2s(v);
                } else {
                    const int nn = row >> 2, bb = row & 3;   // row = n*NGRAPH + b
                    if (mask[bb * NNODE + nn] == 0) v = 0.f;
                    Cf[(size_t)row * N + col] = v;
                }
            }
        }
    }
}

// one block per (head bh, query row n): scores -> softmax -> PV
__global__ __launch_bounds__(256) void attn_kernel(
    const short* __restrict__ qkv,        // [MTOK, QKVN] bf16 bits, q already scaled
    const float* __restrict__ attn_bias,  // [NBH, NNODE, NNODE] fp32
    float* __restrict__ attn)             // [MTOK, EDIM] fp32
{
    const int n = blockIdx.x;
    const int bh = blockIdx.y;
    const int b = bh / NH;
    const int h = bh - b * NH;
    const int t = threadIdx.x;

    __shared__ float qs[HD];
    __shared__ float sm[NNODE];
    __shared__ float red[256];
    __shared__ float part[16][HD];

    const short* qrow = qkv + (size_t)(n * NGRAPH + b) * QKVN + h * HD;
    if (t < HD) qs[t] = s2f(qrow[t]);
    __syncthreads();

    const short* kbase = qkv + (size_t)b * QKVN + EDIM + h * HD;
    const short* vbase = qkv + (size_t)b * QKVN + 2 * EDIM + h * HD;
    const float* brow = attn_bias + ((size_t)bh * NNODE + n) * NNODE;

    // phase 1: scores s[m] = q . k_m + bias
    float lmax = -3e38f;
    #pragma unroll
    for (int j = 0; j < 4; j++) {
        const int m = t + j * 256;
        const bf16x8* kr8 = (const bf16x8*)(kbase + (size_t)m * ROWSTR);
        float s = 0.f;
        #pragma unroll
        for (int c = 0; c < 8; c++) {
            bf16x8 kv = kr8[c];
            #pragma unroll
            for (int u = 0; u < 8; u++) s += qs[c * 8 + u] * s2f(kv[u]);
        }
        s += brow[m];
        sm[m] = s;
        lmax = fmaxf(lmax, s);
    }

    // block max
    red[t] = lmax; __syncthreads();
    for (int off = 128; off > 0; off >>= 1) {
        if (t < off) red[t] = fmaxf(red[t], red[t + off]);
        __syncthreads();
    }
    const float mx = red[0];
    __syncthreads();

    // phase 2: exp + sum
    float lsum = 0.f;
    #pragma unroll
    for (int j = 0; j < 4; j++) {
        const int m = t + j * 256;
        const float p = __expf(sm[m] - mx);
        sm[m] = p;
        lsum += p;
    }
    red[t] = lsum; __syncthreads();
    for (int off = 128; off > 0; off >>= 1) {
        if (t < off) red[t] += red[t + off];
        __syncthreads();
    }
    const float denom = red[0];
    __syncthreads();

    // phase 3: out[d] = sum_m p[m] * v[m,d]; 16 groups x 64 rows, 4 d's per thread
    const int quad = t & 15, g = t >> 4;
    float a0 = 0.f, a1 = 0.f, a2 = 0.f, a3 = 0.f;
    const short* vb = vbase + quad * 4;
    for (int m = g * 64; m < g * 64 + 64; m++) {
        const float p = sm[m];
        bf16x4 vv = *(const bf16x4*)(vb + (size_t)m * ROWSTR);
        a0 += p * s2f(vv[0]);
        a1 += p * s2f(vv[1]);
        a2 += p * s2f(vv[2]);
        a3 += p * s2f(vv[3]);
    }
    part[g][quad * 4 + 0] = a0;
    part[g][quad * 4 + 1] = a1;
    part[g][quad * 4 + 2] = a2;
    part[g][quad * 4 + 3] = a3;
    __syncthreads();

    if (t < HD) {
        float o = 0.f;
        #pragma unroll
        for (int g2 = 0; g2 < 16; g2++) o += part[g2][t];
        o /= denom;
        attn[(size_t)(n * NGRAPH + b) * EDIM + h * HD + t] = o;
    }
}

extern "C" void kernel_launch(void* const* d_in, const int* in_sizes, int n_in,
                              void* d_out, int out_size, void* d_ws, size_t ws_size,
                              hipStream_t stream) {
    const float* query     = (const float*)d_in[0];
    const float* attn_bias = (const float*)d_in[1];
    const int*   mask      = (const int*)d_in[2];
    const float* W_in      = (const float*)d_in[3];
    const float* b_in      = (const float*)d_in[4];
    const float* W_out     = (const float*)d_in[5];
    const float* b_out     = (const float*)d_in[6];
    float* out = (float*)d_out;

    short* qkv  = (short*)d_ws;                       // [MTOK, QKVN] bf16 bits
    float* attn = (float*)(qkv + (size_t)MTOK * QKVN); // [MTOK, EDIM] fp32

    // 1) qkv = query @ W_in^T + b_in  (q part scaled by 0.125), bf16 out
    {
        dim3 grid(MTOK / 64, QKVN / 64);
        gemm_bt<<<grid, 256, 0, stream>>>(query, W_in, b_in, qkv,
                                          MTOK, QKVN, EDIM, 0, nullptr);
    }
    // 2) attention per (head, query-row)
    {
        dim3 grid(NNODE, NBH);
        attn_kernel<<<grid, 256, 0, stream>>>(qkv, attn_bias, attn);
    }
    // 3) out = attn @ W_out^T + b_out, masked, fp32 out
    {
        dim3 grid(MTOK / 64, EDIM / 64);
        gemm_bt<<<grid, 256, 0, stream>>>(attn, W_out, b_out, out,
                                          MTOK, EDIM, EDIM, 1, mask);
    }
}

// Round 3
// 407.667 us; speedup vs baseline: 5.4178x; 5.4178x over previous
//
#include <hip/hip_runtime.h>
#include <hip/hip_bf16.h>

#define NNODE 1024
#define NGRAPH 4
#define EDIM 768
#define NH 12
#define HD 64
#define NBH 48          // NGRAPH*NH
#define MTOK 4096       // NNODE*NGRAPH
#define QKVN 2304       // 3*EDIM

typedef __attribute__((ext_vector_type(8))) short bf16x8;
typedef __attribute__((ext_vector_type(4))) short bf16x4;
typedef __attribute__((ext_vector_type(4))) float f32x4;

// bf16 bits -> float
static __device__ __forceinline__ float s2f(short x) {
    union { unsigned u; float f; } c;
    c.u = ((unsigned)(unsigned short)x) << 16;
    return c.f;
}
// float -> bf16 bits, round-to-nearest-even
static __device__ __forceinline__ short f2s(float f) {
    union { float f; unsigned u; } c; c.f = f;
    unsigned r = (c.u + 0x7FFFu + ((c.u >> 16) & 1u)) >> 16;
    return (short)r;
}

// C[M,N] = A[M,K] @ B[N,K]^T + bias[N].  A,B,bias fp32; compute bf16 MFMA.
// mode 0: scale cols < EDIM by 0.125 (q scaling), C is bf16 (short*)
// mode 1: zero rows whose (b,n) mask is 0 (row = n*NGRAPH + b), C is fp32
__global__ __launch_bounds__(256) void gemm_bt(
    const float* __restrict__ A,
    const float* __restrict__ B,
    const float* __restrict__ bias,
    void* __restrict__ Cv,
    int M, int N, int K, int mode, const int* __restrict__ mask)
{
    const int BK = 32, LDK = 40;
    __shared__ __align__(16) short As[64 * LDK];
    __shared__ __align__(16) short Bs[64 * LDK];

    const int m0 = blockIdx.x * 64;
    const int n0 = blockIdx.y * 64;
    const int t = threadIdx.x;
    const int w = t >> 6, l = t & 63;
    const int wm = (w & 1) * 32, wn = (w >> 1) * 32;
    const int ldr = t >> 2;
    const int ldc = (t & 3) * 8;

    f32x4 acc[2][2];
    #pragma unroll
    for (int i = 0; i < 2; i++)
        #pragma unroll
        for (int j = 0; j < 2; j++)
            acc[i][j] = (f32x4){0.f, 0.f, 0.f, 0.f};

    const int lr = l & 15;
    const int lk = (l >> 4) * 8;

    for (int kt = 0; kt < K; kt += BK) {
        const float* ap = A + (size_t)(m0 + ldr) * K + kt + ldc;
        const float* bp = B + (size_t)(n0 + ldr) * K + kt + ldc;
        float4 a0 = *(const float4*)(ap);
        float4 a1 = *(const float4*)(ap + 4);
        float4 b0 = *(const float4*)(bp);
        float4 b1 = *(const float4*)(bp + 4);
        bf16x8 av, bv;
        av[0] = f2s(a0.x); av[1] = f2s(a0.y); av[2] = f2s(a0.z); av[3] = f2s(a0.w);
        av[4] = f2s(a1.x); av[5] = f2s(a1.y); av[6] = f2s(a1.z); av[7] = f2s(a1.w);
        bv[0] = f2s(b0.x); bv[1] = f2s(b0.y); bv[2] = f2s(b0.z); bv[3] = f2s(b0.w);
        bv[4] = f2s(b1.x); bv[5] = f2s(b1.y); bv[6] = f2s(b1.z); bv[7] = f2s(b1.w);
        *(bf16x8*)(&As[ldr * LDK + ldc]) = av;
        *(bf16x8*)(&Bs[ldr * LDK + ldc]) = bv;
        __syncthreads();

        bf16x8 af0 = *(const bf16x8*)(&As[(wm + lr) * LDK + lk]);
        bf16x8 af1 = *(const bf16x8*)(&As[(wm + 16 + lr) * LDK + lk]);
        bf16x8 bf0 = *(const bf16x8*)(&Bs[(wn + lr) * LDK + lk]);
        bf16x8 bf1 = *(const bf16x8*)(&Bs[(wn + 16 + lr) * LDK + lk]);

        acc[0][0] = __builtin_amdgcn_mfma_f32_16x16x32_bf16(af0, bf0, acc[0][0], 0, 0, 0);
        acc[0][1] = __builtin_amdgcn_mfma_f32_16x16x32_bf16(af0, bf1, acc[0][1], 0, 0, 0);
        acc[1][0] = __builtin_amdgcn_mfma_f32_16x16x32_bf16(af1, bf0, acc[1][0], 0, 0, 0);
        acc[1][1] = __builtin_amdgcn_mfma_f32_16x16x32_bf16(af1, bf1, acc[1][1], 0, 0, 0);
        __syncthreads();
    }

    const int lq = l >> 4;
    short* Cb = (short*)Cv;
    float* Cf = (float*)Cv;
    #pragma unroll
    for (int i = 0; i < 2; i++) {
        #pragma unroll
        for (int j = 0; j < 2; j++) {
            const int col = n0 + wn + j * 16 + lr;
            const float bcol = bias[col];
            #pragma unroll
            for (int r = 0; r < 4; r++) {
                const int row = m0 + wm + i * 16 + lq * 4 + r;
                float v = acc[i][j][r] + bcol;
                if (mode == 0) {
                    if (col < EDIM) v *= 0.125f;
                    Cb[(size_t)row * N + col] = f2s(v);
                } else {
                    const int nn = row >> 2, bb = row & 3;
                    if (mask[bb * NNODE + nn] == 0) v = 0.f;
                    Cf[(size_t)row * N + col] = v;
                }
            }
        }
    }
}

// MFMA flash attention: one block = (64 q-rows) x (1 head). 4 waves, each wave
// owns a 16-row q-strip. K-tiles of 64 keys; online softmax in registers.
#define FLDK 72   // Ks/Vt leading dim (shorts)
#define FLDP 72   // Ps leading dim (shorts)
__global__ __launch_bounds__(256) void flash_attn(
    const short* __restrict__ qkv,        // [MTOK, QKVN] bf16 bits, q pre-scaled
    const float* __restrict__ attn_bias,  // [NBH, NNODE, NNODE] fp32
    float* __restrict__ attn)             // [MTOK, EDIM] fp32
{
    __shared__ __align__(16) short Ks[64 * FLDK];       // [key][k]
    __shared__ __align__(16) short Vt[64 * FLDK];       // [d][key], xor-swizzled
    __shared__ __align__(16) short Ps[4][16 * FLDP];    // per-wave P strip

    const int bh = blockIdx.y;
    const int b = bh / NH, h = bh - b * NH;
    const int q0 = blockIdx.x * 64;
    const int t = threadIdx.x;
    const int w = t >> 6, l = t & 63;
    const int c = l & 15, g = l >> 4;

    // Q A-fragments (rows w*16+c, k = g*8 + j and +32), direct from global
    const int qrow = q0 + w * 16 + c;
    const short* qptr = qkv + (size_t)(qrow * NGRAPH + b) * QKVN + h * HD + g * 8;
    bf16x8 qa0 = *(const bf16x8*)(qptr);
    bf16x8 qa1 = *(const bf16x8*)(qptr + 32);

    // staging indices: thread t loads row (t>>3)+32p, 8 cols (t&7)*8
    const int skrow = t >> 3;
    const int scol8 = (t & 7) * 8;
    const int sxor = scol8 & 0x38;

    float m_st[4], l_st[4];
    f32x4 o[4];
    #pragma unroll
    for (int r = 0; r < 4; r++) { m_st[r] = -3e38f; l_st[r] = 0.f; }
    #pragma unroll
    for (int ct = 0; ct < 4; ct++) o[ct] = (f32x4){0.f, 0.f, 0.f, 0.f};

    const float* brow_base = attn_bias + (size_t)bh * NNODE * NNODE;

    for (int k0 = 0; k0 < NNODE; k0 += 64) {
        __syncthreads();
        #pragma unroll
        for (int p = 0; p < 2; p++) {
            const int kr = skrow + p * 32;
            const short* kvp = qkv + (size_t)((k0 + kr) * NGRAPH + b) * QKVN + h * HD + scol8;
            bf16x8 kk = *(const bf16x8*)(kvp + EDIM);
            bf16x8 vv = *(const bf16x8*)(kvp + 2 * EDIM);
            *(bf16x8*)&Ks[kr * FLDK + scol8] = kk;
            const int kks = kr ^ sxor;           // swizzle: col d=scol8+j, (d&0x38)==sxor
            #pragma unroll
            for (int j = 0; j < 8; j++)
                Vt[(scol8 + j) * FLDK + kks] = vv[j];
        }
        __syncthreads();

        // S = bias + Q K^T   (C-layout: row=g*4+r, col=c within 16-col tile ct)
        f32x4 s[4];
        #pragma unroll
        for (int ct = 0; ct < 4; ct++) {
            #pragma unroll
            for (int r = 0; r < 4; r++)
                s[ct][r] = brow_base[(size_t)(q0 + w * 16 + g * 4 + r) * NNODE + k0 + ct * 16 + c];
        }
        #pragma unroll
        for (int ct = 0; ct < 4; ct++) {
            bf16x8 kb0 = *(const bf16x8*)&Ks[(ct * 16 + c) * FLDK + g * 8];
            bf16x8 kb1 = *(const bf16x8*)&Ks[(ct * 16 + c) * FLDK + 32 + g * 8];
            s[ct] = __builtin_amdgcn_mfma_f32_16x16x32_bf16(qa0, kb0, s[ct], 0, 0, 0);
            s[ct] = __builtin_amdgcn_mfma_f32_16x16x32_bf16(qa1, kb1, s[ct], 0, 0, 0);
        }

        // online softmax: each row (g*4+r) lives in the 16 lanes of group g
        float mn[4], alpha[4];
        #pragma unroll
        for (int r = 0; r < 4; r++) {
            float mx = fmaxf(fmaxf(s[0][r], s[1][r]), fmaxf(s[2][r], s[3][r]));
            #pragma unroll
            for (int off = 1; off < 16; off <<= 1)
                mx = fmaxf(mx, __shfl_xor(mx, off));
            mn[r] = fmaxf(m_st[r], mx);
            alpha[r] = __expf(m_st[r] - mn[r]);
            m_st[r] = mn[r];
        }
        float rs[4] = {0.f, 0.f, 0.f, 0.f};
        #pragma unroll
        for (int ct = 0; ct < 4; ct++) {
            #pragma unroll
            for (int r = 0; r < 4; r++) {
                float pv = __expf(s[ct][r] - mn[r]);
                s[ct][r] = pv;
                rs[r] += pv;
            }
        }
        #pragma unroll
        for (int r = 0; r < 4; r++) {
            #pragma unroll
            for (int off = 1; off < 16; off <<= 1)
                rs[r] += __shfl_xor(rs[r], off);
            l_st[r] = alpha[r] * l_st[r] + rs[r];
        }
        #pragma unroll
        for (int ct = 0; ct < 4; ct++)
            #pragma unroll
            for (int r = 0; r < 4; r++)
                o[ct][r] *= alpha[r];

        // P (C-layout) -> LDS -> A-layout; per-wave private, DS pipe in-order
        short* ps = &Ps[w][0];
        #pragma unroll
        for (int ct = 0; ct < 4; ct++)
            #pragma unroll
            for (int r = 0; r < 4; r++)
                ps[(g * 4 + r) * FLDP + ct * 16 + c] = f2s(s[ct][r]);

        bf16x8 pa0 = *(const bf16x8*)&ps[c * FLDP + g * 8];
        bf16x8 pa1 = *(const bf16x8*)&ps[c * FLDP + 32 + g * 8];
        #pragma unroll
        for (int ct = 0; ct < 4; ct++) {
            const int d = ct * 16 + c;
            const int x = d & 0x38;
            bf16x8 vb0 = *(const bf16x8*)&Vt[d * FLDK + ((g * 8) ^ x)];
            bf16x8 vb1 = *(const bf16x8*)&Vt[d * FLDK + ((32 + g * 8) ^ x)];
            o[ct] = __builtin_amdgcn_mfma_f32_16x16x32_bf16(pa0, vb0, o[ct], 0, 0, 0);
            o[ct] = __builtin_amdgcn_mfma_f32_16x16x32_bf16(pa1, vb1, o[ct], 0, 0, 0);
        }
    }

    float inv[4];
    #pragma unroll
    for (int r = 0; r < 4; r++) inv[r] = 1.f / l_st[r];
    #pragma unroll
    for (int ct = 0; ct < 4; ct++) {
        #pragma unroll
        for (int r = 0; r < 4; r++) {
            const int n = q0 + w * 16 + g * 4 + r;
            attn[(size_t)(n * NGRAPH + b) * EDIM + h * HD + ct * 16 + c] = o[ct][r] * inv[r];
        }
    }
}

extern "C" void kernel_launch(void* const* d_in, const int* in_sizes, int n_in,
                              void* d_out, int out_size, void* d_ws, size_t ws_size,
                              hipStream_t stream) {
    const float* query     = (const float*)d_in[0];
    const float* attn_bias = (const float*)d_in[1];
    const int*   mask      = (const int*)d_in[2];
    const float* W_in      = (const float*)d_in[3];
    const float* b_in      = (const float*)d_in[4];
    const float* W_out     = (const float*)d_in[5];
    const float* b_out     = (const float*)d_in[6];
    float* out = (float*)d_out;

    short* qkv  = (short*)d_ws;                        // [MTOK, QKVN] bf16 bits
    float* attn = (float*)(qkv + (size_t)MTOK * QKVN); // [MTOK, EDIM] fp32

    // 1) qkv = query @ W_in^T + b_in  (q part scaled by 0.125), bf16 out
    {
        dim3 grid(MTOK / 64, QKVN / 64);
        gemm_bt<<<grid, 256, 0, stream>>>(query, W_in, b_in, qkv,
                                          MTOK, QKVN, EDIM, 0, nullptr);
    }
    // 2) MFMA flash attention
    {
        dim3 grid(NNODE / 64, NBH);
        flash_attn<<<grid, 256, 0, stream>>>(qkv, attn_bias, attn);
    }
    // 3) out = attn @ W_out^T + b_out, masked, fp32 out
    {
        dim3 grid(MTOK / 64, EDIM / 64);
        gemm_bt<<<grid, 256, 0, stream>>>(attn, W_out, b_out, out,
                                          MTOK, EDIM, EDIM, 1, mask);
    }
}

// Round 4
// 364.902 us; speedup vs baseline: 6.0528x; 1.1172x over previous
//
#include <hip/hip_runtime.h>
#include <hip/hip_bf16.h>

#define NNODE 1024
#define NGRAPH 4
#define EDIM 768
#define NH 12
#define HD 64
#define NBH 48          // NGRAPH*NH
#define MTOK 4096       // NNODE*NGRAPH
#define QKVN 2304       // 3*EDIM

typedef __attribute__((ext_vector_type(8))) short bf16x8;
typedef __attribute__((ext_vector_type(4))) short bf16x4;
typedef __attribute__((ext_vector_type(4))) float f32x4;

// float -> bf16 bits, round-to-nearest-even
static __device__ __forceinline__ short f2s(float f) {
    union { float f; unsigned u; } c; c.f = f;
    unsigned r = (c.u + 0x7FFFu + ((c.u >> 16) & 1u)) >> 16;
    return (short)r;
}

// fp32 -> bf16 elementwise, n divisible by 2048 (grid = n/2048, block 256)
__global__ __launch_bounds__(256) void cvt_bf16(
    const float* __restrict__ in, short* __restrict__ out, int n)
{
    const int i = (blockIdx.x * 256 + threadIdx.x) * 8;
    float4 a = *(const float4*)(in + i);
    float4 b = *(const float4*)(in + i + 4);
    bf16x8 v;
    v[0] = f2s(a.x); v[1] = f2s(a.y); v[2] = f2s(a.z); v[3] = f2s(a.w);
    v[4] = f2s(b.x); v[5] = f2s(b.y); v[6] = f2s(b.z); v[7] = f2s(b.w);
    *(bf16x8*)(out + i) = v;
}

// C[M,N] = A[M,K] @ B[N,K]^T + bias[N].  A,B bf16 bits; bias fp32.
// mode 0: scale cols < EDIM by 0.125 (q scaling), C is bf16 (short*)
// mode 1: zero rows whose (b,n) mask is 0 (row = n*NGRAPH + b), C is fp32
__global__ __launch_bounds__(256) void gemm_bt(
    const short* __restrict__ A,
    const short* __restrict__ B,
    const float* __restrict__ bias,
    void* __restrict__ Cv,
    int M, int N, int K, int mode, const int* __restrict__ mask)
{
    const int LDK = 72;   // 64 + 8 pad
    __shared__ __align__(16) short As[64 * LDK];
    __shared__ __align__(16) short Bs[64 * LDK];

    const int m0 = blockIdx.x * 64;
    const int n0 = blockIdx.y * 64;
    const int t = threadIdx.x;
    const int w = t >> 6, l = t & 63;
    const int wm = (w & 1) * 32, wn = (w >> 1) * 32;
    const int ldr = t >> 2;          // 0..63
    const int ldc = (t & 3) * 16;    // 0,16,32,48

    f32x4 acc[2][2];
    #pragma unroll
    for (int i = 0; i < 2; i++)
        #pragma unroll
        for (int j = 0; j < 2; j++)
            acc[i][j] = (f32x4){0.f, 0.f, 0.f, 0.f};

    const int lr = l & 15;
    const int lk = (l >> 4) * 8;

    for (int kt = 0; kt < K; kt += 64) {
        const short* ap = A + (size_t)(m0 + ldr) * K + kt + ldc;
        const short* bp = B + (size_t)(n0 + ldr) * K + kt + ldc;
        uint4 a0 = *(const uint4*)(ap);
        uint4 a1 = *(const uint4*)(ap + 8);
        uint4 b0 = *(const uint4*)(bp);
        uint4 b1 = *(const uint4*)(bp + 8);
        *(uint4*)(&As[ldr * LDK + ldc]) = a0;
        *(uint4*)(&As[ldr * LDK + ldc + 8]) = a1;
        *(uint4*)(&Bs[ldr * LDK + ldc]) = b0;
        *(uint4*)(&Bs[ldr * LDK + ldc + 8]) = b1;
        __syncthreads();

        #pragma unroll
        for (int ks = 0; ks < 2; ks++) {
            bf16x8 af0 = *(const bf16x8*)(&As[(wm + lr) * LDK + ks * 32 + lk]);
            bf16x8 af1 = *(const bf16x8*)(&As[(wm + 16 + lr) * LDK + ks * 32 + lk]);
            bf16x8 bf0 = *(const bf16x8*)(&Bs[(wn + lr) * LDK + ks * 32 + lk]);
            bf16x8 bf1 = *(const bf16x8*)(&Bs[(wn + 16 + lr) * LDK + ks * 32 + lk]);
            acc[0][0] = __builtin_amdgcn_mfma_f32_16x16x32_bf16(af0, bf0, acc[0][0], 0, 0, 0);
            acc[0][1] = __builtin_amdgcn_mfma_f32_16x16x32_bf16(af0, bf1, acc[0][1], 0, 0, 0);
            acc[1][0] = __builtin_amdgcn_mfma_f32_16x16x32_bf16(af1, bf0, acc[1][0], 0, 0, 0);
            acc[1][1] = __builtin_amdgcn_mfma_f32_16x16x32_bf16(af1, bf1, acc[1][1], 0, 0, 0);
        }
        __syncthreads();
    }

    // epilogue: C/D layout col = lane&15, row = (lane>>4)*4 + reg
    const int lq = l >> 4;
    short* Cb = (short*)Cv;
    float* Cf = (float*)Cv;
    #pragma unroll
    for (int i = 0; i < 2; i++) {
        #pragma unroll
        for (int j = 0; j < 2; j++) {
            const int col = n0 + wn + j * 16 + lr;
            const float bcol = bias[col];
            #pragma unroll
            for (int r = 0; r < 4; r++) {
                const int row = m0 + wm + i * 16 + lq * 4 + r;
                float v = acc[i][j][r] + bcol;
                if (mode == 0) {
                    if (col < EDIM) v *= 0.125f;
                    Cb[(size_t)row * N + col] = f2s(v);
                } else {
                    const int nn = row >> 2, bb = row & 3;
                    if (mask[bb * NNODE + nn] == 0) v = 0.f;
                    Cf[(size_t)row * N + col] = v;
                }
            }
        }
    }
}

// MFMA flash attention: one block = (64 q-rows) x (1 head). 4 waves, each wave
// owns a 16-row q-strip. K-tiles of 64 keys; online softmax in registers;
// bias register-prefetched one tile ahead. Output written as bf16.
#define FLDK 72
#define FLDP 72
__global__ __launch_bounds__(256) void flash_attn(
    const short* __restrict__ qkv,        // [MTOK, QKVN] bf16 bits, q pre-scaled
    const float* __restrict__ attn_bias,  // [NBH, NNODE, NNODE] fp32
    short* __restrict__ attn)             // [MTOK, EDIM] bf16 bits
{
    __shared__ __align__(16) short Ks[64 * FLDK];       // [key][k]
    __shared__ __align__(16) short Vt[64 * FLDK];       // [d][key], xor-swizzled
    __shared__ __align__(16) short Ps[4][16 * FLDP];    // per-wave P strip

    const int bh = blockIdx.y;
    const int b = bh / NH, h = bh - b * NH;
    const int q0 = blockIdx.x * 64;
    const int t = threadIdx.x;
    const int w = t >> 6, l = t & 63;
    const int c = l & 15, g = l >> 4;

    // Q A-fragments (rows w*16+c, k = g*8 + j and +32), direct from global
    const int qrow = q0 + w * 16 + c;
    const short* qptr = qkv + (size_t)(qrow * NGRAPH + b) * QKVN + h * HD + g * 8;
    bf16x8 qa0 = *(const bf16x8*)(qptr);
    bf16x8 qa1 = *(const bf16x8*)(qptr + 32);

    // staging indices: thread t loads row (t>>3)+32p, 8 cols (t&7)*8
    const int skrow = t >> 3;
    const int scol8 = (t & 7) * 8;
    const int sxor = scol8 & 0x38;

    float m_st[4], l_st[4];
    f32x4 o[4];
    #pragma unroll
    for (int r = 0; r < 4; r++) { m_st[r] = -3e38f; l_st[r] = 0.f; }
    #pragma unroll
    for (int ct = 0; ct < 4; ct++) o[ct] = (f32x4){0.f, 0.f, 0.f, 0.f};

    // bias prefetch: element (ct,r) = bp_base[(g*4+r)*NNODE + k0 + ct*16 + c]
    const float* bp_base = attn_bias + (size_t)bh * NNODE * NNODE
                         + (size_t)(q0 + w * 16) * NNODE;
    float bpre[16];
    #pragma unroll
    for (int ct = 0; ct < 4; ct++)
        #pragma unroll
        for (int r = 0; r < 4; r++)
            bpre[ct * 4 + r] = bp_base[(size_t)(g * 4 + r) * NNODE + ct * 16 + c];

    for (int k0 = 0; k0 < NNODE; k0 += 64) {
        __syncthreads();
        #pragma unroll
        for (int p = 0; p < 2; p++) {
            const int kr = skrow + p * 32;
            const short* kvp = qkv + (size_t)((k0 + kr) * NGRAPH + b) * QKVN + h * HD + scol8;
            bf16x8 kk = *(const bf16x8*)(kvp + EDIM);
            bf16x8 vv = *(const bf16x8*)(kvp + 2 * EDIM);
            *(bf16x8*)&Ks[kr * FLDK + scol8] = kk;
            const int kks = kr ^ sxor;
            #pragma unroll
            for (int j = 0; j < 8; j++)
                Vt[(scol8 + j) * FLDK + kks] = vv[j];
        }
        __syncthreads();

        // S = bias + Q K^T (C-layout), consume prefetched bias, refill for next tile
        f32x4 s[4];
        #pragma unroll
        for (int ct = 0; ct < 4; ct++)
            #pragma unroll
            for (int r = 0; r < 4; r++)
                s[ct][r] = bpre[ct * 4 + r];

        const int knext = (k0 + 64) & (NNODE - 1);   // wrap: last-tile reload of tile 0
        #pragma unroll
        for (int ct = 0; ct < 4; ct++)
            #pragma unroll
            for (int r = 0; r < 4; r++)
                bpre[ct * 4 + r] = bp_base[(size_t)(g * 4 + r) * NNODE + knext + ct * 16 + c];

        #pragma unroll
        for (int ct = 0; ct < 4; ct++) {
            bf16x8 kb0 = *(const bf16x8*)&Ks[(ct * 16 + c) * FLDK + g * 8];
            bf16x8 kb1 = *(const bf16x8*)&Ks[(ct * 16 + c) * FLDK + 32 + g * 8];
            s[ct] = __builtin_amdgcn_mfma_f32_16x16x32_bf16(qa0, kb0, s[ct], 0, 0, 0);
            s[ct] = __builtin_amdgcn_mfma_f32_16x16x32_bf16(qa1, kb1, s[ct], 0, 0, 0);
        }

        // online softmax: each row (g*4+r) lives in the 16 lanes of group g
        float mn[4], alpha[4];
        #pragma unroll
        for (int r = 0; r < 4; r++) {
            float mx = fmaxf(fmaxf(s[0][r], s[1][r]), fmaxf(s[2][r], s[3][r]));
            #pragma unroll
            for (int off = 1; off < 16; off <<= 1)
                mx = fmaxf(mx, __shfl_xor(mx, off));
            mn[r] = fmaxf(m_st[r], mx);
            alpha[r] = __expf(m_st[r] - mn[r]);
            m_st[r] = mn[r];
        }
        float rs[4] = {0.f, 0.f, 0.f, 0.f};
        #pragma unroll
        for (int ct = 0; ct < 4; ct++) {
            #pragma unroll
            for (int r = 0; r < 4; r++) {
                float pv = __expf(s[ct][r] - mn[r]);
                s[ct][r] = pv;
                rs[r] += pv;
            }
        }
        #pragma unroll
        for (int r = 0; r < 4; r++) {
            #pragma unroll
            for (int off = 1; off < 16; off <<= 1)
                rs[r] += __shfl_xor(rs[r], off);
            l_st[r] = alpha[r] * l_st[r] + rs[r];
        }
        #pragma unroll
        for (int ct = 0; ct < 4; ct++)
            #pragma unroll
            for (int r = 0; r < 4; r++)
                o[ct][r] *= alpha[r];

        // P (C-layout) -> LDS -> A-layout; per-wave private (in-order DS pipe)
        short* ps = &Ps[w][0];
        #pragma unroll
        for (int ct = 0; ct < 4; ct++)
            #pragma unroll
            for (int r = 0; r < 4; r++)
                ps[(g * 4 + r) * FLDP + ct * 16 + c] = f2s(s[ct][r]);

        bf16x8 pa0 = *(const bf16x8*)&ps[c * FLDP + g * 8];
        bf16x8 pa1 = *(const bf16x8*)&ps[c * FLDP + 32 + g * 8];
        #pragma unroll
        for (int ct = 0; ct < 4; ct++) {
            const int d = ct * 16 + c;
            const int x = d & 0x38;
            bf16x8 vb0 = *(const bf16x8*)&Vt[d * FLDK + ((g * 8) ^ x)];
            bf16x8 vb1 = *(const bf16x8*)&Vt[d * FLDK + ((32 + g * 8) ^ x)];
            o[ct] = __builtin_amdgcn_mfma_f32_16x16x32_bf16(pa0, vb0, o[ct], 0, 0, 0);
            o[ct] = __builtin_amdgcn_mfma_f32_16x16x32_bf16(pa1, vb1, o[ct], 0, 0, 0);
        }
    }

    float inv[4];
    #pragma unroll
    for (int r = 0; r < 4; r++) inv[r] = 1.f / l_st[r];
    #pragma unroll
    for (int ct = 0; ct < 4; ct++) {
        #pragma unroll
        for (int r = 0; r < 4; r++) {
            const int n = q0 + w * 16 + g * 4 + r;
            attn[(size_t)(n * NGRAPH + b) * EDIM + h * HD + ct * 16 + c] =
                f2s(o[ct][r] * inv[r]);
        }
    }
}

extern "C" void kernel_launch(void* const* d_in, const int* in_sizes, int n_in,
                              void* d_out, int out_size, void* d_ws, size_t ws_size,
                              hipStream_t stream) {
    const float* query     = (const float*)d_in[0];
    const float* attn_bias = (const float*)d_in[1];
    const int*   mask      = (const int*)d_in[2];
    const float* W_in      = (const float*)d_in[3];
    const float* b_in      = (const float*)d_in[4];
    const float* W_out     = (const float*)d_in[5];
    const float* b_out     = (const float*)d_in[6];
    float* out = (float*)d_out;

    // workspace layout (shorts): qkv | attn | q_bf | win_bf | wout_bf
    short* qkv     = (short*)d_ws;                       // [MTOK, QKVN]
    short* attn    = qkv + (size_t)MTOK * QKVN;          // [MTOK, EDIM]
    short* q_bf    = attn + (size_t)MTOK * EDIM;         // [MTOK, EDIM]
    short* win_bf  = q_bf + (size_t)MTOK * EDIM;         // [QKVN, EDIM]
    short* wout_bf = win_bf + (size_t)QKVN * EDIM;       // [EDIM, EDIM]

    // 0) convert fp32 -> bf16
    cvt_bf16<<<(MTOK * EDIM) / 2048, 256, 0, stream>>>(query, q_bf, MTOK * EDIM);
    cvt_bf16<<<(QKVN * EDIM) / 2048, 256, 0, stream>>>(W_in, win_bf, QKVN * EDIM);
    cvt_bf16<<<(EDIM * EDIM) / 2048, 256, 0, stream>>>(W_out, wout_bf, EDIM * EDIM);

    // 1) qkv = q_bf @ W_in^T + b_in  (q part scaled by 0.125), bf16 out
    {
        dim3 grid(MTOK / 64, QKVN / 64);
        gemm_bt<<<grid, 256, 0, stream>>>(q_bf, win_bf, b_in, qkv,
                                          MTOK, QKVN, EDIM, 0, nullptr);
    }
    // 2) MFMA flash attention (bf16 out)
    {
        dim3 grid(NNODE / 64, NBH);
        flash_attn<<<grid, 256, 0, stream>>>(qkv, attn_bias, attn);
    }
    // 3) out = attn @ W_out^T + b_out, masked, fp32 out
    {
        dim3 grid(MTOK / 64, EDIM / 64);
        gemm_bt<<<grid, 256, 0, stream>>>(attn, wout_bf, b_out, out,
                                          MTOK, EDIM, EDIM, 1, mask);
    }
}